// Round 8
// baseline (646.511 us; speedup 1.0000x reference)
//
#include <hip/hip_runtime.h>

#define NN 100000
#define NE 200000
#define MT (NN + NE)

typedef unsigned short u16;
typedef unsigned int u32;
typedef __attribute__((ext_vector_type(8))) short bf16x8;
typedef __attribute__((ext_vector_type(4))) float f32x4;

__device__ __forceinline__ float bf2f(u16 u) {
    union { u32 i; float f; } v; v.i = ((u32)u) << 16; return v.f;
}
__device__ __forceinline__ u16 f2bf(float f) {
    union { u32 i; float f; } v; v.f = f;
    u32 r = v.i + 0x7fffu + ((v.i >> 16) & 1u);
    return (u16)(r >> 16);
}
__device__ __forceinline__ void unpack2(u32 u, float& lo, float& hi) {
    union { u32 i; float f; } a, b;
    a.i = u << 16; b.i = u & 0xffff0000u;
    lo = a.f; hi = b.f;
}
__device__ __forceinline__ u32 pack2(float a, float b) {
    return (u32)f2bf(a) | ((u32)f2bf(b) << 16);
}
__device__ __forceinline__ float loadf(const void* p, size_t i, int f32) {
    return f32 ? ((const float*)p)[i] : bf2f(((const u16*)p)[i]);
}

// Detect input dtype from bit patterns of x. flag=1 => fp32. (R7-proven: fires 1.)
__global__ void detect_kernel(const u32* __restrict__ x, int* flag) {
    __shared__ int cnt;
    if (threadIdx.x == 0) cnt = 0;
    __syncthreads();
    int bad = 0;
    for (int i = threadIdx.x; i < 1024; i += 256) {
        u32 e = (x[i] >> 7) & 0xFF;
        if (e == 0xFF || (e > 0 && (e < 107 || e > 134))) bad++;
    }
    atomicAdd(&cnt, bad);
    __syncthreads();
    if (threadIdx.x == 0) *flag = (cnt > 256) ? 1 : 0;
}

// Build MFMA B-operand fragments (bf16) and summed f32 biases.
// Feature interleave: matrix m (of 5) maps to blocks (2m, 2m+1);
// feature f = 2*(lane&15) + (b&1), k = (lane>>4)*8 + j.
// So acc[2m] holds even features, acc[2m+1] odd, at col = lane&15 —
// lets the gemm epilogue pack each (even,odd) pair into one u32 ds_write.
// x side m: [theta_x | theta_deg | theta_r0 | theta_r1 | gamma_x]
// y side m: [gamma_y | gamma_deg | gamma_r0 | gamma_r1 | theta_y]
__global__ __launch_bounds__(256) void prep_kernel(
    const void* txw, const void* tdw, const void* tyw,
    const void* gyw, const void* gdw, const void* gxw,
    const void* trw, const void* grw,
    const void* txb, const void* tdb, const void* tyb,
    const void* gyb, const void* gdb, const void* gxb,
    const void* trb, const void* grb,
    u16* Bfx, u16* Bfy, float* bx, float* by, const int* flagp)
{
    int f32 = *flagp;
    int t = blockIdx.x * 256 + threadIdx.x;
    if (t < 10240) {
        int side = t / 5120;
        int e = t - side * 5120;
        int b = e >> 9, lane = (e >> 3) & 63, j = e & 7;
        int m = b >> 1;
        int k = ((lane >> 4) << 3) + j;
        int f = ((lane & 15) << 1) | (b & 1);
        size_t idx = (size_t)k * 32 + f;
        float v;
        if (side == 0) {
            v = (m == 0) ? loadf(txw, idx, f32) : (m == 1) ? loadf(tdw, idx, f32)
              : (m == 2) ? loadf(trw, idx, f32) : (m == 3) ? loadf(trw, 1024 + idx, f32)
              : loadf(gxw, idx, f32);
            Bfx[e] = f2bf(v);
        } else {
            v = (m == 0) ? loadf(gyw, idx, f32) : (m == 1) ? loadf(gdw, idx, f32)
              : (m == 2) ? loadf(grw, idx, f32) : (m == 3) ? loadf(grw, 1024 + idx, f32)
              : loadf(tyw, idx, f32);
            Bfy[e] = f2bf(v);
        }
    } else if (t < 10304) {
        int f = t - 10240;
        if (f < 32) {
            bx[f] = loadf(txb, f, f32) + loadf(tdb, f, f32) + loadf(tyb, f, f32)
                  + loadf(trb, f, f32) + loadf(trb, 32 + f, f32);
        } else {
            f -= 32;
            by[f] = loadf(gyb, f, f32) + loadf(gdb, f, f32) + loadf(gxb, f, f32)
                  + loadf(grb, f, f32) + loadf(grb, 32 + f, f32);
        }
    }
}

// MFMA GEMM: per wave, 16 rows x 160 cols in 10 mfma_f32_16x16x32_bf16.
// Epilogue: aligned LDS transpose (u32 packed writes thanks to the feature
// interleave) -> 16-B coalesced global stores. R7's 32 scalar 2-B stores per
// lane were the store-bound bottleneck (~170 us hidden in the profile).
__global__ __launch_bounds__(256, 4) void gemm2(
    const void* __restrict__ x, const void* __restrict__ y,
    const u16* __restrict__ Bfx, const u16* __restrict__ Bfy,
    const float* __restrict__ bx, const float* __restrict__ by,
    const void* __restrict__ deg_g, const void* __restrict__ deg_lg,
    const int* __restrict__ dst,
    u16* __restrict__ Xself, u16* __restrict__ Xt,
    u16* __restrict__ Xtt,   u16* __restrict__ Xaux,
    u16* __restrict__ Yself, u16* __restrict__ Yt, u16* __restrict__ Ytt,
    float* __restrict__ xacc, const int* __restrict__ flagp)
{
    __shared__ __align__(16) u16 sbuf[4][4][512];   // [wave][array][16r x 32c]
    int f32 = *flagp;
    int lane = threadIdx.x & 63;
    int wib  = threadIdx.x >> 6;
    bool is_y = (blockIdx.x >= 1563);                 // x: 1563 blocks, y: 3125
    int wid = (is_y ? (int)blockIdx.x - 1563 : (int)blockIdx.x) * 4 + wib;
    int nwaves = is_y ? 12500 : 6250;
    if (wid >= nwaves) return;
    int r0 = wid * 16;

    const void* feat = is_y ? y : x;
    const u16* Bf   = is_y ? Bfy : Bfx;
    const float* bias = is_y ? by : bx;
    const void* deg  = is_y ? deg_lg : deg_g;

    // A fragment: lane holds A[m=lane&15][k=(lane>>4)*8 + j].
    union { u16 s[8]; bf16x8 v; } au;
    {
        size_t eoff = (size_t)(r0 + (lane & 15)) * 32 + ((lane >> 4) << 3);
        if (f32) {
            const float4* fp = (const float4*)((const float*)feat + eoff);
            float4 A0 = fp[0], A1 = fp[1];
            au.s[0] = f2bf(A0.x); au.s[1] = f2bf(A0.y);
            au.s[2] = f2bf(A0.z); au.s[3] = f2bf(A0.w);
            au.s[4] = f2bf(A1.x); au.s[5] = f2bf(A1.y);
            au.s[6] = f2bf(A1.z); au.s[7] = f2bf(A1.w);
        } else {
            au.v = *(const bf16x8*)((const u16*)feat + eoff);
        }
    }
    f32x4 acc[10];
    const u16* bp = Bf + lane * 8;
#pragma unroll
    for (int b = 0; b < 10; ++b) {
        bf16x8 bfr = *(const bf16x8*)(bp + b * 512);
        f32x4 z = {0.f, 0.f, 0.f, 0.f};
        acc[b] = __builtin_amdgcn_mfma_f32_16x16x32_bf16(au.v, bfr, z, 0, 0, 0);
    }

    // D layout: col = lane&15, row = (lane>>4)*4 + i; features (2n, 2n+1).
    int n = lane & 15, quad = lane >> 4;
    int rowb = r0 + quad * 4;
    float bev = bias[2 * n], bov = bias[2 * n + 1];

#pragma unroll
    for (int i = 0; i < 4; ++i) {
        float dgi = loadf(deg, rowb + i, f32);
        int rr = (quad * 4 + i) * 32 + 2 * n;
        *(u32*)&sbuf[wib][0][rr] = pack2(acc[0][i] + dgi * acc[2][i] + bev,
                                         acc[1][i] + dgi * acc[3][i] + bov);
        *(u32*)&sbuf[wib][1][rr] = pack2(acc[4][i], acc[5][i]);
        *(u32*)&sbuf[wib][2][rr] = pack2(acc[6][i], acc[7][i]);
        if (!is_y)
            *(u32*)&sbuf[wib][3][rr] = pack2(acc[8][i], acc[9][i]);
    }
    __asm__ volatile("s_waitcnt lgkmcnt(0)" ::: "memory");   // intra-wave ds flush

    int lr = lane >> 2, ch = (lane & 3) * 8;          // 16 rows x 16-B chunks
    int lo = lr * 32 + ch;
    size_t go = (size_t)(r0 + lr) * 32 + ch;
    if (!is_y) {
        *(uint4*)(Xself + go) = *(const uint4*)&sbuf[wib][0][lo];
        *(uint4*)(Xt   + go)  = *(const uint4*)&sbuf[wib][1][lo];
        *(uint4*)(Xtt  + go)  = *(const uint4*)&sbuf[wib][2][lo];
        *(uint4*)(Xaux + go)  = *(const uint4*)&sbuf[wib][3][lo];
    } else {
        *(uint4*)(Yself + go) = *(const uint4*)&sbuf[wib][0][lo];
        *(uint4*)(Yt   + go)  = *(const uint4*)&sbuf[wib][1][lo];
        *(uint4*)(Ytt  + go)  = *(const uint4*)&sbuf[wib][2][lo];
#pragma unroll
        for (int i = 0; i < 4; ++i) {
            int d = dst[rowb + i];
            float* p = xacc + (size_t)d * 32;
            atomicAdd(p + 2 * n,     acc[8][i]);
            atomicAdd(p + 2 * n + 1, acc[9][i]);
        }
    }
}

// Fused x+y gather. Thread per (row, quarter): 8 features via 16-B gathers,
// 4-deep load staging. launch_bounds(256,6) caps VGPR ~84 (R7: 100 VGPR,
// occ 20%) — occupancy experiment vs the 2.6 TB/s random-gather plateau.
__global__ __launch_bounds__(256, 6) void gather_fused(
    const u16* __restrict__ Xself, const u16* __restrict__ Xt,
    const u16* __restrict__ Xtt,   const u16* __restrict__ Xaux,
    const u16* __restrict__ Yself, const u16* __restrict__ Yt,
    const u16* __restrict__ Ytt,
    const float* __restrict__ xacc,
    const int* __restrict__ t_g, const int* __restrict__ tt_g,
    const int* __restrict__ t_lg, const int* __restrict__ tt_lg,
    const int* __restrict__ pm_pd,
    u16* __restrict__ pre_h,                   // [MT,32] bf16 (x rows, then y)
    float* __restrict__ stats)                 // [sx|qx|sy|qy], 32 each
{
    __shared__ int s_t[1024];
    __shared__ int s_tt[1024];
    __shared__ float s_sum[32];
    __shared__ float s_sq[32];
    bool is_y = (blockIdx.x >= 1563);
    int M = is_y ? NE : NN;
    const u16 *Self, *T, *TT;
    const int *tl, *ttl;
    if (is_y) { Self = Yself; T = Yt; TT = Ytt; tl = t_lg; ttl = tt_lg; }
    else      { Self = Xself; T = Xt; TT = Xtt; tl = t_g;  ttl = tt_g; }
    float* ss = stats + (is_y ? 64 : 0);

    if (threadIdx.x < 32) { s_sum[threadIdx.x] = 0.f; s_sq[threadIdx.x] = 0.f; }
    int row0 = (is_y ? (int)blockIdx.x - 1563 : (int)blockIdx.x) * 64;
    int lim = (M - row0) * 16;
    for (int i = threadIdx.x; i < 1024; i += 256) {
        s_t[i]  = (i < lim) ? tl[row0 * 16 + i]  : 0;
        s_tt[i] = (i < lim) ? ttl[row0 * 16 + i] : 0;
    }
    __syncthreads();

    int lr = threadIdx.x >> 2, q = threadIdx.x & 3;
    int r = row0 + lr;
    bool act = r < M;
    int rc = act ? r : row0;

    float a[8];
    {
        uint4 u = *(const uint4*)(Self + (size_t)rc * 32 + q * 8);
        unpack2(u.x, a[0], a[1]); unpack2(u.y, a[2], a[3]);
        unpack2(u.z, a[4], a[5]); unpack2(u.w, a[6], a[7]);
    }
    const int* il  = &s_t[lr * 16];
    const int* ill = &s_tt[lr * 16];
#pragma unroll
    for (int batch = 0; batch < 4; ++batch) {
        uint4 g[4];
#pragma unroll
        for (int j = 0; j < 4; ++j)
            g[j] = *(const uint4*)(T + (size_t)il[batch * 4 + j] * 32 + q * 8);
#pragma unroll
        for (int j = 0; j < 4; ++j) {
            float e0, e1, e2, e3, e4, e5, e6, e7;
            unpack2(g[j].x, e0, e1); unpack2(g[j].y, e2, e3);
            unpack2(g[j].z, e4, e5); unpack2(g[j].w, e6, e7);
            a[0] += e0; a[1] += e1; a[2] += e2; a[3] += e3;
            a[4] += e4; a[5] += e5; a[6] += e6; a[7] += e7;
        }
    }
#pragma unroll
    for (int batch = 0; batch < 4; ++batch) {
        uint4 g[4];
#pragma unroll
        for (int j = 0; j < 4; ++j)
            g[j] = *(const uint4*)(TT + (size_t)ill[batch * 4 + j] * 32 + q * 8);
#pragma unroll
        for (int j = 0; j < 4; ++j) {
            float e0, e1, e2, e3, e4, e5, e6, e7;
            unpack2(g[j].x, e0, e1); unpack2(g[j].y, e2, e3);
            unpack2(g[j].z, e4, e5); unpack2(g[j].w, e6, e7);
            a[0] += e0; a[1] += e1; a[2] += e2; a[3] += e3;
            a[4] += e4; a[5] += e5; a[6] += e6; a[7] += e7;
        }
    }
    if (!is_y) {
        float4 b0 = *(const float4*)(xacc + (size_t)rc * 32 + q * 8);
        float4 b1 = *(const float4*)(xacc + (size_t)rc * 32 + q * 8 + 4);
        a[0] += b0.x; a[1] += b0.y; a[2] += b0.z; a[3] += b0.w;
        a[4] += b1.x; a[5] += b1.y; a[6] += b1.z; a[7] += b1.w;
    } else {
        int ai = pm_pd[rc];
        uint4 g = *(const uint4*)(Xaux + (size_t)ai * 32 + q * 8);
        float e0, e1, e2, e3, e4, e5, e6, e7;
        unpack2(g.x, e0, e1); unpack2(g.y, e2, e3);
        unpack2(g.z, e4, e5); unpack2(g.w, e6, e7);
        a[0] += e0; a[1] += e1; a[2] += e2; a[3] += e3;
        a[4] += e4; a[5] += e5; a[6] += e6; a[7] += e7;
    }
    if (q >= 2) {
#pragma unroll
        for (int i = 0; i < 8; ++i) a[i] = fmaxf(a[i], 0.f);
    }
    if (act) {
        size_t orow = (size_t)(is_y ? NN + r : r) * 32 + q * 8;
        uint4 o;
        o.x = pack2(a[0], a[1]); o.y = pack2(a[2], a[3]);
        o.z = pack2(a[4], a[5]); o.w = pack2(a[6], a[7]);
        *(uint4*)(pre_h + orow) = o;
    } else {
#pragma unroll
        for (int i = 0; i < 8; ++i) a[i] = 0.f;
    }
#pragma unroll
    for (int i = 0; i < 8; ++i) {
        atomicAdd(&s_sum[q * 8 + i], a[i]);
        atomicAdd(&s_sq[q * 8 + i], a[i] * a[i]);
    }
    __syncthreads();
    if (threadIdx.x < 32) {
        atomicAdd(&ss[threadIdx.x], s_sum[threadIdx.x]);
        atomicAdd(&ss[32 + threadIdx.x], s_sq[threadIdx.x]);
    }
}

__global__ void finalize_stats(
    const float* stats,
    const void* bnxw, const void* bnxb, const void* bnyw, const void* bnyb,
    float* scsh, const int* flagp)
{
    int f32 = *flagp;
    int f = threadIdx.x;
    if (f < 32) {
        float m = stats[f] / (float)NN;
        float var = stats[32 + f] / (float)NN - m * m;
        float inv = rsqrtf(var + 1e-5f);
        float sc = loadf(bnxw, f, f32) * inv;
        scsh[f] = sc; scsh[32 + f] = loadf(bnxb, f, f32) - m * sc;
    } else if (f < 64) {
        int g = f - 32;
        float m = stats[64 + g] / (float)NE;
        float var = stats[96 + g] / (float)NE - m * m;
        float inv = rsqrtf(var + 1e-5f);
        float sc = loadf(bnyw, g, f32) * inv;
        scsh[64 + g] = sc; scsh[96 + g] = loadf(bnyb, g, f32) - m * sc;
    }
}

__global__ __launch_bounds__(256) void apply_bn(
    const u16* __restrict__ pre_h, const float* __restrict__ scsh,
    void* __restrict__ out, const int* __restrict__ flagp)
{
    int f32 = *flagp;
    int tid = blockIdx.x * 256 + threadIdx.x;   // MT*8 threads, 4 elems each
    if (tid >= MT * 8) return;
    int fq = (tid & 7) * 4;
    const float* sc = (tid < NN * 8) ? scsh : scsh + 64;
    ushort4 u = ((const ushort4*)pre_h)[tid];
    float o0 = bf2f(u.x) * sc[fq + 0] + sc[32 + fq + 0];
    float o1 = bf2f(u.y) * sc[fq + 1] + sc[32 + fq + 1];
    float o2 = bf2f(u.z) * sc[fq + 2] + sc[32 + fq + 2];
    float o3 = bf2f(u.w) * sc[fq + 3] + sc[32 + fq + 3];
    if (f32) {
        float4 o; o.x = o0; o.y = o1; o.z = o2; o.w = o3;
        ((float4*)out)[tid] = o;
    } else {
        ushort4 o; o.x = f2bf(o0); o.y = f2bf(o1); o.z = f2bf(o2); o.w = f2bf(o3);
        ((ushort4*)out)[tid] = o;
    }
}

extern "C" void kernel_launch(void* const* d_in, const int* in_sizes, int n_in,
                              void* d_out, int out_size, void* d_ws, size_t ws_size,
                              hipStream_t stream)
{
    const void* x      = d_in[0];
    const void* y      = d_in[1];
    const void* deg_g  = d_in[2];
    const void* deg_lg = d_in[3];
    const int* t_g   = (const int*)d_in[4];
    const int* tt_g  = (const int*)d_in[5];
    const int* t_lg  = (const int*)d_in[6];
    const int* tt_lg = (const int*)d_in[7];
    const int* dst   = (const int*)d_in[8];
    const int* pm_pd = (const int*)d_in[9];

    char* ws = (char*)d_ws;
    int*   flag = (int*)ws;                     // 4 B
    u16* Bfx   = (u16*)(ws + 256);              // 5120 u16 = 10 KB
    u16* Bfy   = Bfx + 5120;                    // 10 KB
    float* bx  = (float*)(ws + 24576);          // 32 f32
    float* by  = bx + 32;
    float* stats = by + 32;                     // 128 f32
    float* scsh  = stats + 128;                 // 128 f32
    u16* Xself = (u16*)(ws + 65536);            // NN*32 = 6.4 MB each
    u16* Xt    = Xself + (size_t)NN * 32;
    u16* Xtt   = Xt    + (size_t)NN * 32;
    u16* Xaux  = Xtt   + (size_t)NN * 32;
    u16* Yself = Xaux  + (size_t)NN * 32;       // NE*32 = 12.8 MB each
    u16* Yt    = Yself + (size_t)NE * 32;
    u16* Ytt   = Yt    + (size_t)NE * 32;
    float* xacc = (float*)(Ytt + (size_t)NE * 32);   // NN*32 f32 = 12.8 MB
    u16* pre_h = (u16*)(xacc + (size_t)NN * 32);     // MT*32 bf16 = 19.2 MB
    // total ~ 96 MB

    hipMemsetAsync(stats, 0, 256 * sizeof(float), stream);
    hipMemsetAsync(xacc, 0, (size_t)NN * 32 * sizeof(float), stream);

    detect_kernel<<<1, 256, 0, stream>>>((const u32*)x, flag);
    prep_kernel<<<41, 256, 0, stream>>>(
        d_in[10], d_in[12], d_in[14], d_in[16], d_in[18], d_in[20],
        d_in[22], d_in[24],
        d_in[11], d_in[13], d_in[15], d_in[17], d_in[19], d_in[21],
        d_in[23], d_in[25],
        Bfx, Bfy, bx, by, flag);
    gemm2<<<4688, 256, 0, stream>>>(x, y, Bfx, Bfy, bx, by, deg_g, deg_lg, dst,
                                    Xself, Xt, Xtt, Xaux, Yself, Yt, Ytt,
                                    xacc, flag);
    gather_fused<<<4688, 256, 0, stream>>>(Xself, Xt, Xtt, Xaux, Yself, Yt, Ytt,
                                           xacc, t_g, tt_g, t_lg, tt_lg, pm_pd,
                                           pre_h, stats);
    finalize_stats<<<1, 64, 0, stream>>>(stats, d_in[26], d_in[27], d_in[28],
                                         d_in[29], scsh, flag);
    apply_bn<<<9375, 256, 0, stream>>>(pre_h, scsh, d_out, flag);
}

// Round 9
// 444.660 us; speedup vs baseline: 1.4539x; 1.4539x over previous
//
#include <hip/hip_runtime.h>

#define NN 100000
#define NE 200000
#define MT (NN + NE)

typedef unsigned short u16;
typedef unsigned int u32;
typedef __attribute__((ext_vector_type(8))) short bf16x8;
typedef __attribute__((ext_vector_type(4))) float f32x4;

__device__ __forceinline__ float bf2f(u16 u) {
    union { u32 i; float f; } v; v.i = ((u32)u) << 16; return v.f;
}
__device__ __forceinline__ u16 f2bf(float f) {
    union { u32 i; float f; } v; v.f = f;
    u32 r = v.i + 0x7fffu + ((v.i >> 16) & 1u);
    return (u16)(r >> 16);
}
__device__ __forceinline__ void unpack2(u32 u, float& lo, float& hi) {
    union { u32 i; float f; } a, b;
    a.i = u << 16; b.i = u & 0xffff0000u;
    lo = a.f; hi = b.f;
}
__device__ __forceinline__ u32 pack2(float a, float b) {
    return (u32)f2bf(a) | ((u32)f2bf(b) << 16);
}
__device__ __forceinline__ float loadf(const void* p, size_t i, int f32) {
    return f32 ? ((const float*)p)[i] : bf2f(((const u16*)p)[i]);
}

// Detect input dtype from bit patterns of x. flag=1 => fp32. (Proven: fires 1.)
__global__ void detect_kernel(const u32* __restrict__ x, int* flag) {
    __shared__ int cnt;
    if (threadIdx.x == 0) cnt = 0;
    __syncthreads();
    int bad = 0;
    for (int i = threadIdx.x; i < 1024; i += 256) {
        u32 e = (x[i] >> 7) & 0xFF;
        if (e == 0xFF || (e > 0 && (e < 107 || e > 134))) bad++;
    }
    atomicAdd(&cnt, bad);
    __syncthreads();
    if (threadIdx.x == 0) *flag = (cnt > 256) ? 1 : 0;
}

// Build MFMA B-operand fragments (bf16) and summed f32 biases.
// Feature interleave: matrix m (of 5) -> blocks (2m, 2m+1);
// feature f = 2*(lane&15) + (b&1), k = (lane>>4)*8 + j.
// x side m: [theta_x | theta_deg | theta_r0 | theta_r1 | gamma_x]
// y side m: [gamma_y | gamma_deg | gamma_r0 | gamma_r1 | theta_y]
__global__ __launch_bounds__(256) void prep_kernel(
    const void* txw, const void* tdw, const void* tyw,
    const void* gyw, const void* gdw, const void* gxw,
    const void* trw, const void* grw,
    const void* txb, const void* tdb, const void* tyb,
    const void* gyb, const void* gdb, const void* gxb,
    const void* trb, const void* grb,
    u16* Bfx, u16* Bfy, float* bx, float* by, const int* flagp)
{
    int f32 = *flagp;
    int t = blockIdx.x * 256 + threadIdx.x;
    if (t < 10240) {
        int side = t / 5120;
        int e = t - side * 5120;
        int b = e >> 9, lane = (e >> 3) & 63, j = e & 7;
        int m = b >> 1;
        int k = ((lane >> 4) << 3) + j;
        int f = ((lane & 15) << 1) | (b & 1);
        size_t idx = (size_t)k * 32 + f;
        float v;
        if (side == 0) {
            v = (m == 0) ? loadf(txw, idx, f32) : (m == 1) ? loadf(tdw, idx, f32)
              : (m == 2) ? loadf(trw, idx, f32) : (m == 3) ? loadf(trw, 1024 + idx, f32)
              : loadf(gxw, idx, f32);
            Bfx[e] = f2bf(v);
        } else {
            v = (m == 0) ? loadf(gyw, idx, f32) : (m == 1) ? loadf(gdw, idx, f32)
              : (m == 2) ? loadf(grw, idx, f32) : (m == 3) ? loadf(grw, 1024 + idx, f32)
              : loadf(tyw, idx, f32);
            Bfy[e] = f2bf(v);
        }
    } else if (t < 10304) {
        int f = t - 10240;
        if (f < 32) {
            bx[f] = loadf(txb, f, f32) + loadf(tdb, f, f32) + loadf(tyb, f, f32)
                  + loadf(trb, f, f32) + loadf(trb, 32 + f, f32);
        } else {
            f -= 32;
            by[f] = loadf(gyb, f, f32) + loadf(gdb, f, f32) + loadf(gxb, f, f32)
                  + loadf(grb, f, f32) + loadf(grb, 32 + f, f32);
        }
    }
}

// Side-generic MFMA GEMM: per wave 16 rows x 160 cols (10 mfma_16x16x32_bf16).
// NO atomics (moved to scatter_y for profile attribution). Writes Self
// (= m0 + deg*m1 + bias), T, TT, Aux via aligned LDS transpose.
__global__ __launch_bounds__(256, 4) void gemm_side(
    const void* __restrict__ feat, const u16* __restrict__ Bf,
    const float* __restrict__ bias, const void* __restrict__ deg,
    u16* __restrict__ Self, u16* __restrict__ T,
    u16* __restrict__ TT,   u16* __restrict__ Aux,
    int nwaves, const int* __restrict__ flagp)
{
    __shared__ __align__(16) u16 sbuf[4][4][512];   // [wave][array][16r x 32c]
    int f32 = *flagp;
    int lane = threadIdx.x & 63;
    int wib  = threadIdx.x >> 6;
    int wid = blockIdx.x * 4 + wib;
    if (wid >= nwaves) return;
    int r0 = wid * 16;

    // A fragment: lane holds A[m=lane&15][k=(lane>>4)*8 + j].
    union { u16 s[8]; bf16x8 v; } au;
    {
        size_t eoff = (size_t)(r0 + (lane & 15)) * 32 + ((lane >> 4) << 3);
        if (f32) {
            const float4* fp = (const float4*)((const float*)feat + eoff);
            float4 A0 = fp[0], A1 = fp[1];
            au.s[0] = f2bf(A0.x); au.s[1] = f2bf(A0.y);
            au.s[2] = f2bf(A0.z); au.s[3] = f2bf(A0.w);
            au.s[4] = f2bf(A1.x); au.s[5] = f2bf(A1.y);
            au.s[6] = f2bf(A1.z); au.s[7] = f2bf(A1.w);
        } else {
            au.v = *(const bf16x8*)((const u16*)feat + eoff);
        }
    }
    f32x4 acc[10];
    const u16* bp = Bf + lane * 8;
#pragma unroll
    for (int b = 0; b < 10; ++b) {
        bf16x8 bfr = *(const bf16x8*)(bp + b * 512);
        f32x4 z = {0.f, 0.f, 0.f, 0.f};
        acc[b] = __builtin_amdgcn_mfma_f32_16x16x32_bf16(au.v, bfr, z, 0, 0, 0);
    }

    // D layout: col = lane&15, row = (lane>>4)*4 + i; features (2n, 2n+1).
    int n = lane & 15, quad = lane >> 4;
    int rowb = r0 + quad * 4;
    float bev = bias[2 * n], bov = bias[2 * n + 1];

#pragma unroll
    for (int i = 0; i < 4; ++i) {
        float dgi = loadf(deg, rowb + i, f32);
        int rr = (quad * 4 + i) * 32 + 2 * n;
        *(u32*)&sbuf[wib][0][rr] = pack2(acc[0][i] + dgi * acc[2][i] + bev,
                                         acc[1][i] + dgi * acc[3][i] + bov);
        *(u32*)&sbuf[wib][1][rr] = pack2(acc[4][i], acc[5][i]);
        *(u32*)&sbuf[wib][2][rr] = pack2(acc[6][i], acc[7][i]);
        *(u32*)&sbuf[wib][3][rr] = pack2(acc[8][i], acc[9][i]);
    }
    __asm__ volatile("s_waitcnt lgkmcnt(0)" ::: "memory");   // intra-wave only

    int lr = lane >> 2, ch = (lane & 3) * 8;          // 16 rows x 16-B chunks
    int lo = lr * 32 + ch;
    size_t go = (size_t)(r0 + lr) * 32 + ch;
    *(uint4*)(Self + go) = *(const uint4*)&sbuf[wib][0][lo];
    *(uint4*)(T   + go)  = *(const uint4*)&sbuf[wib][1][lo];
    *(uint4*)(TT  + go)  = *(const uint4*)&sbuf[wib][2][lo];
    *(uint4*)(Aux + go)  = *(const uint4*)&sbuf[wib][3][lo];
}

// Isolated segment-sum scatter: xacc[dst[e]] += Yaux[e] (f32 atomics).
// 16 threads/edge, 2 features each. This names the suspected ~170 us
// atomic cost in the profile.
__global__ __launch_bounds__(256) void scatter_y(
    const u16* __restrict__ Yaux, const int* __restrict__ dst,
    float* __restrict__ xacc)
{
    int tid = blockIdx.x * 256 + threadIdx.x;
    if (tid >= NE * 16) return;
    int e = tid >> 4, p = tid & 15;
    int d = dst[e];
    u32 pair = *(const u32*)(Yaux + (size_t)e * 32 + 2 * p);
    float lo, hi;
    unpack2(pair, lo, hi);
    float* px = xacc + (size_t)d * 32 + 2 * p;
    atomicAdd(px, lo);
    atomicAdd(px + 1, hi);
}

// Fused x+y gather — R7-proven shape (batch-8 staging, no min-waves bound;
// R8's (256,6) forced VGPR 40 -> 802 MB spill WRITE). Thread per (row,
// quarter): 8 features via 16-B gathers.
__global__ __launch_bounds__(256) void gather_fused(
    const u16* __restrict__ Xself, const u16* __restrict__ Xt,
    const u16* __restrict__ Xtt,   const u16* __restrict__ Xaux,
    const u16* __restrict__ Yself, const u16* __restrict__ Yt,
    const u16* __restrict__ Ytt,
    const float* __restrict__ xacc,
    const int* __restrict__ t_g, const int* __restrict__ tt_g,
    const int* __restrict__ t_lg, const int* __restrict__ tt_lg,
    const int* __restrict__ pm_pd,
    u16* __restrict__ pre_h,                   // [MT,32] bf16 (x rows, then y)
    float* __restrict__ stats)                 // [sx|qx|sy|qy], 32 each
{
    __shared__ int s_t[1024];
    __shared__ int s_tt[1024];
    __shared__ float s_sum[32];
    __shared__ float s_sq[32];
    bool is_y = (blockIdx.x >= 1563);
    int M = is_y ? NE : NN;
    const u16 *Self, *T, *TT;
    const int *tl, *ttl;
    if (is_y) { Self = Yself; T = Yt; TT = Ytt; tl = t_lg; ttl = tt_lg; }
    else      { Self = Xself; T = Xt; TT = Xtt; tl = t_g;  ttl = tt_g; }
    float* ss = stats + (is_y ? 64 : 0);

    if (threadIdx.x < 32) { s_sum[threadIdx.x] = 0.f; s_sq[threadIdx.x] = 0.f; }
    int row0 = (is_y ? (int)blockIdx.x - 1563 : (int)blockIdx.x) * 64;
    int lim = (M - row0) * 16;
    for (int i = threadIdx.x; i < 1024; i += 256) {
        s_t[i]  = (i < lim) ? tl[row0 * 16 + i]  : 0;
        s_tt[i] = (i < lim) ? ttl[row0 * 16 + i] : 0;
    }
    __syncthreads();

    int lr = threadIdx.x >> 2, q = threadIdx.x & 3;
    int r = row0 + lr;
    bool act = r < M;
    int rc = act ? r : row0;

    float a[8];
    {
        uint4 u = *(const uint4*)(Self + (size_t)rc * 32 + q * 8);
        unpack2(u.x, a[0], a[1]); unpack2(u.y, a[2], a[3]);
        unpack2(u.z, a[4], a[5]); unpack2(u.w, a[6], a[7]);
    }
    const int* il  = &s_t[lr * 16];
    const int* ill = &s_tt[lr * 16];
#pragma unroll
    for (int batch = 0; batch < 2; ++batch) {
        uint4 g[8];
#pragma unroll
        for (int j = 0; j < 8; ++j)
            g[j] = *(const uint4*)(T + (size_t)il[batch * 8 + j] * 32 + q * 8);
#pragma unroll
        for (int j = 0; j < 8; ++j) {
            float e0, e1, e2, e3, e4, e5, e6, e7;
            unpack2(g[j].x, e0, e1); unpack2(g[j].y, e2, e3);
            unpack2(g[j].z, e4, e5); unpack2(g[j].w, e6, e7);
            a[0] += e0; a[1] += e1; a[2] += e2; a[3] += e3;
            a[4] += e4; a[5] += e5; a[6] += e6; a[7] += e7;
        }
    }
#pragma unroll
    for (int batch = 0; batch < 2; ++batch) {
        uint4 g[8];
#pragma unroll
        for (int j = 0; j < 8; ++j)
            g[j] = *(const uint4*)(TT + (size_t)ill[batch * 8 + j] * 32 + q * 8);
#pragma unroll
        for (int j = 0; j < 8; ++j) {
            float e0, e1, e2, e3, e4, e5, e6, e7;
            unpack2(g[j].x, e0, e1); unpack2(g[j].y, e2, e3);
            unpack2(g[j].z, e4, e5); unpack2(g[j].w, e6, e7);
            a[0] += e0; a[1] += e1; a[2] += e2; a[3] += e3;
            a[4] += e4; a[5] += e5; a[6] += e6; a[7] += e7;
        }
    }
    if (!is_y) {
        float4 b0 = *(const float4*)(xacc + (size_t)rc * 32 + q * 8);
        float4 b1 = *(const float4*)(xacc + (size_t)rc * 32 + q * 8 + 4);
        a[0] += b0.x; a[1] += b0.y; a[2] += b0.z; a[3] += b0.w;
        a[4] += b1.x; a[5] += b1.y; a[6] += b1.z; a[7] += b1.w;
    } else {
        int ai = pm_pd[rc];
        uint4 g = *(const uint4*)(Xaux + (size_t)ai * 32 + q * 8);
        float e0, e1, e2, e3, e4, e5, e6, e7;
        unpack2(g.x, e0, e1); unpack2(g.y, e2, e3);
        unpack2(g.z, e4, e5); unpack2(g.w, e6, e7);
        a[0] += e0; a[1] += e1; a[2] += e2; a[3] += e3;
        a[4] += e4; a[5] += e5; a[6] += e6; a[7] += e7;
    }
    if (q >= 2) {
#pragma unroll
        for (int i = 0; i < 8; ++i) a[i] = fmaxf(a[i], 0.f);
    }
    if (act) {
        size_t orow = (size_t)(is_y ? NN + r : r) * 32 + q * 8;
        uint4 o;
        o.x = pack2(a[0], a[1]); o.y = pack2(a[2], a[3]);
        o.z = pack2(a[4], a[5]); o.w = pack2(a[6], a[7]);
        *(uint4*)(pre_h + orow) = o;
    } else {
#pragma unroll
        for (int i = 0; i < 8; ++i) a[i] = 0.f;
    }
#pragma unroll
    for (int i = 0; i < 8; ++i) {
        atomicAdd(&s_sum[q * 8 + i], a[i]);
        atomicAdd(&s_sq[q * 8 + i], a[i] * a[i]);
    }
    __syncthreads();
    if (threadIdx.x < 32) {
        atomicAdd(&ss[threadIdx.x], s_sum[threadIdx.x]);
        atomicAdd(&ss[32 + threadIdx.x], s_sq[threadIdx.x]);
    }
}

__global__ void finalize_stats(
    const float* stats,
    const void* bnxw, const void* bnxb, const void* bnyw, const void* bnyb,
    float* scsh, const int* flagp)
{
    int f32 = *flagp;
    int f = threadIdx.x;
    if (f < 32) {
        float m = stats[f] / (float)NN;
        float var = stats[32 + f] / (float)NN - m * m;
        float inv = rsqrtf(var + 1e-5f);
        float sc = loadf(bnxw, f, f32) * inv;
        scsh[f] = sc; scsh[32 + f] = loadf(bnxb, f, f32) - m * sc;
    } else if (f < 64) {
        int g = f - 32;
        float m = stats[64 + g] / (float)NE;
        float var = stats[96 + g] / (float)NE - m * m;
        float inv = rsqrtf(var + 1e-5f);
        float sc = loadf(bnyw, g, f32) * inv;
        scsh[64 + g] = sc; scsh[96 + g] = loadf(bnyb, g, f32) - m * sc;
    }
}

__global__ __launch_bounds__(256) void apply_bn(
    const u16* __restrict__ pre_h, const float* __restrict__ scsh,
    void* __restrict__ out, const int* __restrict__ flagp)
{
    int f32 = *flagp;
    int tid = blockIdx.x * 256 + threadIdx.x;   // MT*8 threads, 4 elems each
    if (tid >= MT * 8) return;
    int fq = (tid & 7) * 4;
    const float* sc = (tid < NN * 8) ? scsh : scsh + 64;
    ushort4 u = ((const ushort4*)pre_h)[tid];
    float o0 = bf2f(u.x) * sc[fq + 0] + sc[32 + fq + 0];
    float o1 = bf2f(u.y) * sc[fq + 1] + sc[32 + fq + 1];
    float o2 = bf2f(u.z) * sc[fq + 2] + sc[32 + fq + 2];
    float o3 = bf2f(u.w) * sc[fq + 3] + sc[32 + fq + 3];
    if (f32) {
        float4 o; o.x = o0; o.y = o1; o.z = o2; o.w = o3;
        ((float4*)out)[tid] = o;
    } else {
        ushort4 o; o.x = f2bf(o0); o.y = f2bf(o1); o.z = f2bf(o2); o.w = f2bf(o3);
        ((ushort4*)out)[tid] = o;
    }
}

extern "C" void kernel_launch(void* const* d_in, const int* in_sizes, int n_in,
                              void* d_out, int out_size, void* d_ws, size_t ws_size,
                              hipStream_t stream)
{
    const void* x      = d_in[0];
    const void* y      = d_in[1];
    const void* deg_g  = d_in[2];
    const void* deg_lg = d_in[3];
    const int* t_g   = (const int*)d_in[4];
    const int* tt_g  = (const int*)d_in[5];
    const int* t_lg  = (const int*)d_in[6];
    const int* tt_lg = (const int*)d_in[7];
    const int* dst   = (const int*)d_in[8];
    const int* pm_pd = (const int*)d_in[9];

    char* ws = (char*)d_ws;
    int*   flag = (int*)ws;                     // 4 B
    u16* Bfx   = (u16*)(ws + 256);              // 5120 u16 = 10 KB
    u16* Bfy   = Bfx + 5120;                    // 10 KB
    float* bx  = (float*)(ws + 24576);          // 32 f32
    float* by  = bx + 32;
    float* stats = by + 32;                     // 128 f32
    float* scsh  = stats + 128;                 // 128 f32
    u16* Xself = (u16*)(ws + 65536);            // NN*32 = 6.4 MB each
    u16* Xt    = Xself + (size_t)NN * 32;
    u16* Xtt   = Xt    + (size_t)NN * 32;
    u16* Xaux  = Xtt   + (size_t)NN * 32;
    u16* Yself = Xaux  + (size_t)NN * 32;       // NE*32 = 12.8 MB each
    u16* Yt    = Yself + (size_t)NE * 32;
    u16* Ytt   = Yt    + (size_t)NE * 32;
    u16* Yaux  = Ytt   + (size_t)NE * 32;       // NEW: 12.8 MB
    float* xacc = (float*)(Yaux + (size_t)NE * 32);  // NN*32 f32 = 12.8 MB
    u16* pre_h = (u16*)(xacc + (size_t)NN * 32);     // MT*32 bf16 = 19.2 MB
    // total ~ 109 MB

    hipMemsetAsync(stats, 0, 256 * sizeof(float), stream);
    hipMemsetAsync(xacc, 0, (size_t)NN * 32 * sizeof(float), stream);

    detect_kernel<<<1, 256, 0, stream>>>((const u32*)x, flag);
    prep_kernel<<<41, 256, 0, stream>>>(
        d_in[10], d_in[12], d_in[14], d_in[16], d_in[18], d_in[20],
        d_in[22], d_in[24],
        d_in[11], d_in[13], d_in[15], d_in[17], d_in[19], d_in[21],
        d_in[23], d_in[25],
        Bfx, Bfy, bx, by, flag);
    gemm_side<<<1563, 256, 0, stream>>>(x, Bfx, bx, deg_g,
                                        Xself, Xt, Xtt, Xaux, 6250, flag);
    gemm_side<<<3125, 256, 0, stream>>>(y, Bfy, by, deg_lg,
                                        Yself, Yt, Ytt, Yaux, 12500, flag);
    scatter_y<<<12500, 256, 0, stream>>>(Yaux, dst, xacc);
    gather_fused<<<4688, 256, 0, stream>>>(Xself, Xt, Xtt, Xaux, Yself, Yt, Ytt,
                                           xacc, t_g, tt_g, t_lg, tt_lg, pm_pd,
                                           pre_h, stats);
    finalize_stats<<<1, 64, 0, stream>>>(stats, d_in[26], d_in[27], d_in[28],
                                         d_in[29], scsh, flag);
    apply_bn<<<9375, 256, 0, stream>>>(pre_h, scsh, d_out, flag);
}

// Round 10
// 433.578 us; speedup vs baseline: 1.4911x; 1.0256x over previous
//
#include <hip/hip_runtime.h>

#define NN 100000
#define NE 200000
#define MT (NN + NE)
#define ECAP 16   // in-degree cap; dst ~ Poisson(2), P(>16) ~ 1e-10

typedef unsigned short u16;
typedef unsigned int u32;
typedef __attribute__((ext_vector_type(8))) short bf16x8;
typedef __attribute__((ext_vector_type(4))) float f32x4;

__device__ __forceinline__ float bf2f(u16 u) {
    union { u32 i; float f; } v; v.i = ((u32)u) << 16; return v.f;
}
__device__ __forceinline__ u16 f2bf(float f) {
    union { u32 i; float f; } v; v.f = f;
    u32 r = v.i + 0x7fffu + ((v.i >> 16) & 1u);
    return (u16)(r >> 16);
}
__device__ __forceinline__ void unpack2(u32 u, float& lo, float& hi) {
    union { u32 i; float f; } a, b;
    a.i = u << 16; b.i = u & 0xffff0000u;
    lo = a.f; hi = b.f;
}
__device__ __forceinline__ u32 pack2(float a, float b) {
    return (u32)f2bf(a) | ((u32)f2bf(b) << 16);
}
__device__ __forceinline__ float loadf(const void* p, size_t i, int f32) {
    return f32 ? ((const float*)p)[i] : bf2f(((const u16*)p)[i]);
}

// Detect input dtype from bit patterns of x. flag=1 => fp32. (Proven: fires 1.)
__global__ void detect_kernel(const u32* __restrict__ x, int* flag) {
    __shared__ int cnt;
    if (threadIdx.x == 0) cnt = 0;
    __syncthreads();
    int bad = 0;
    for (int i = threadIdx.x; i < 1024; i += 256) {
        u32 e = (x[i] >> 7) & 0xFF;
        if (e == 0xFF || (e > 0 && (e < 107 || e > 134))) bad++;
    }
    atomicAdd(&cnt, bad);
    __syncthreads();
    if (threadIdx.x == 0) *flag = (cnt > 256) ? 1 : 0;
}

// Build MFMA B-operand fragments (bf16) and summed f32 biases.
// Feature interleave: matrix m (of 5) -> blocks (2m, 2m+1);
// feature f = 2*(lane&15) + (b&1), k = (lane>>4)*8 + j.
// x side m: [theta_x | theta_deg | theta_r0 | theta_r1 | gamma_x]
// y side m: [gamma_y | gamma_deg | gamma_r0 | gamma_r1 | theta_y]
__global__ __launch_bounds__(256) void prep_kernel(
    const void* txw, const void* tdw, const void* tyw,
    const void* gyw, const void* gdw, const void* gxw,
    const void* trw, const void* grw,
    const void* txb, const void* tdb, const void* tyb,
    const void* gyb, const void* gdb, const void* gxb,
    const void* trb, const void* grb,
    u16* Bfx, u16* Bfy, float* bx, float* by, const int* flagp)
{
    int f32 = *flagp;
    int t = blockIdx.x * 256 + threadIdx.x;
    if (t < 10240) {
        int side = t / 5120;
        int e = t - side * 5120;
        int b = e >> 9, lane = (e >> 3) & 63, j = e & 7;
        int m = b >> 1;
        int k = ((lane >> 4) << 3) + j;
        int f = ((lane & 15) << 1) | (b & 1);
        size_t idx = (size_t)k * 32 + f;
        float v;
        if (side == 0) {
            v = (m == 0) ? loadf(txw, idx, f32) : (m == 1) ? loadf(tdw, idx, f32)
              : (m == 2) ? loadf(trw, idx, f32) : (m == 3) ? loadf(trw, 1024 + idx, f32)
              : loadf(gxw, idx, f32);
            Bfx[e] = f2bf(v);
        } else {
            v = (m == 0) ? loadf(gyw, idx, f32) : (m == 1) ? loadf(gdw, idx, f32)
              : (m == 2) ? loadf(grw, idx, f32) : (m == 3) ? loadf(grw, 1024 + idx, f32)
              : loadf(tyw, idx, f32);
            Bfy[e] = f2bf(v);
        }
    } else if (t < 10304) {
        int f = t - 10240;
        if (f < 32) {
            bx[f] = loadf(txb, f, f32) + loadf(tdb, f, f32) + loadf(tyb, f, f32)
                  + loadf(trb, f, f32) + loadf(trb, 32 + f, f32);
        } else {
            f -= 32;
            by[f] = loadf(gyb, f, f32) + loadf(gdb, f, f32) + loadf(gxb, f, f32)
                  + loadf(grb, f, f32) + loadf(grb, 32 + f, f32);
        }
    }
}

// Side-generic MFMA GEMM: per wave 16 rows x 160 cols (10 mfma_16x16x32_bf16).
// Writes Self (= m0 + deg*m1 + bias), T, TT, Aux via aligned LDS transpose.
__global__ __launch_bounds__(256, 4) void gemm_side(
    const void* __restrict__ feat, const u16* __restrict__ Bf,
    const float* __restrict__ bias, const void* __restrict__ deg,
    u16* __restrict__ Self, u16* __restrict__ T,
    u16* __restrict__ TT,   u16* __restrict__ Aux,
    int nwaves, const int* __restrict__ flagp)
{
    __shared__ __align__(16) u16 sbuf[4][4][512];   // [wave][array][16r x 32c]
    int f32 = *flagp;
    int lane = threadIdx.x & 63;
    int wib  = threadIdx.x >> 6;
    int wid = blockIdx.x * 4 + wib;
    if (wid >= nwaves) return;
    int r0 = wid * 16;

    // A fragment: lane holds A[m=lane&15][k=(lane>>4)*8 + j].
    union { u16 s[8]; bf16x8 v; } au;
    {
        size_t eoff = (size_t)(r0 + (lane & 15)) * 32 + ((lane >> 4) << 3);
        if (f32) {
            const float4* fp = (const float4*)((const float*)feat + eoff);
            float4 A0 = fp[0], A1 = fp[1];
            au.s[0] = f2bf(A0.x); au.s[1] = f2bf(A0.y);
            au.s[2] = f2bf(A0.z); au.s[3] = f2bf(A0.w);
            au.s[4] = f2bf(A1.x); au.s[5] = f2bf(A1.y);
            au.s[6] = f2bf(A1.z); au.s[7] = f2bf(A1.w);
        } else {
            au.v = *(const bf16x8*)((const u16*)feat + eoff);
        }
    }
    f32x4 acc[10];
    const u16* bp = Bf + lane * 8;
#pragma unroll
    for (int b = 0; b < 10; ++b) {
        bf16x8 bfr = *(const bf16x8*)(bp + b * 512);
        f32x4 z = {0.f, 0.f, 0.f, 0.f};
        acc[b] = __builtin_amdgcn_mfma_f32_16x16x32_bf16(au.v, bfr, z, 0, 0, 0);
    }

    // D layout: col = lane&15, row = (lane>>4)*4 + i; features (2n, 2n+1).
    int n = lane & 15, quad = lane >> 4;
    int rowb = r0 + quad * 4;
    float bev = bias[2 * n], bov = bias[2 * n + 1];

#pragma unroll
    for (int i = 0; i < 4; ++i) {
        float dgi = loadf(deg, rowb + i, f32);
        int rr = (quad * 4 + i) * 32 + 2 * n;
        *(u32*)&sbuf[wib][0][rr] = pack2(acc[0][i] + dgi * acc[2][i] + bev,
                                         acc[1][i] + dgi * acc[3][i] + bov);
        *(u32*)&sbuf[wib][1][rr] = pack2(acc[4][i], acc[5][i]);
        *(u32*)&sbuf[wib][2][rr] = pack2(acc[6][i], acc[7][i]);
        *(u32*)&sbuf[wib][3][rr] = pack2(acc[8][i], acc[9][i]);
    }
    __asm__ volatile("s_waitcnt lgkmcnt(0)" ::: "memory");   // intra-wave only

    int lr = lane >> 2, ch = (lane & 3) * 8;          // 16 rows x 16-B chunks
    int lo = lr * 32 + ch;
    size_t go = (size_t)(r0 + lr) * 32 + ch;
    *(uint4*)(Self + go) = *(const uint4*)&sbuf[wib][0][lo];
    *(uint4*)(T   + go)  = *(const uint4*)&sbuf[wib][1][lo];
    *(uint4*)(TT  + go)  = *(const uint4*)&sbuf[wib][2][lo];
    *(uint4*)(Aux + go)  = *(const uint4*)&sbuf[wib][3][lo];
}

// Build inverted index of dst: per-node incoming-edge bucket lists.
// 200K int atomics (vs 6.4M f32 atomics of the scatter approach).
// Overflow beyond ECAP (P ~ 1e-10): direct f32 atomic fallback into xacc.
__global__ __launch_bounds__(256) void fill_edges(
    const int* __restrict__ dst, int* __restrict__ cnt,
    int* __restrict__ elist, const u16* __restrict__ Yaux,
    float* __restrict__ xacc)
{
    int e = blockIdx.x * 256 + threadIdx.x;
    if (e >= NE) return;
    int d = dst[e];
    int pos = atomicAdd(&cnt[d], 1);
    if (pos < ECAP) {
        elist[(size_t)d * ECAP + pos] = e;
    } else {
        const u16* yr = Yaux + (size_t)e * 32;
        float* px = xacc + (size_t)d * 32;
        for (int f = 0; f < 32; ++f) atomicAdd(px + f, bf2f(yr[f]));
    }
}

// Fused x+y gather. Thread per (row, quarter): 8 features via 16-B gathers,
// batch-8 staging (R7-proven; no min-waves bound — R8's (256,6) caused spill).
// x-side pulls segment-sum via inverted index (cnt/elist -> Yaux rows).
__global__ __launch_bounds__(256) void gather_fused(
    const u16* __restrict__ Xself, const u16* __restrict__ Xt,
    const u16* __restrict__ Xtt,   const u16* __restrict__ Xaux,
    const u16* __restrict__ Yself, const u16* __restrict__ Yt,
    const u16* __restrict__ Ytt,   const u16* __restrict__ Yaux,
    const float* __restrict__ xacc,
    const int* __restrict__ cnt,   const int* __restrict__ elist,
    const int* __restrict__ t_g, const int* __restrict__ tt_g,
    const int* __restrict__ t_lg, const int* __restrict__ tt_lg,
    const int* __restrict__ pm_pd,
    u16* __restrict__ pre_h,                   // [MT,32] bf16 (x rows, then y)
    float* __restrict__ stats)                 // [sx|qx|sy|qy], 32 each
{
    __shared__ int s_t[1024];
    __shared__ int s_tt[1024];
    __shared__ float s_sum[32];
    __shared__ float s_sq[32];
    bool is_y = (blockIdx.x >= 1563);
    int M = is_y ? NE : NN;
    const u16 *Self, *T, *TT;
    const int *tl, *ttl;
    if (is_y) { Self = Yself; T = Yt; TT = Ytt; tl = t_lg; ttl = tt_lg; }
    else      { Self = Xself; T = Xt; TT = Xtt; tl = t_g;  ttl = tt_g; }
    float* ss = stats + (is_y ? 64 : 0);

    if (threadIdx.x < 32) { s_sum[threadIdx.x] = 0.f; s_sq[threadIdx.x] = 0.f; }
    int row0 = (is_y ? (int)blockIdx.x - 1563 : (int)blockIdx.x) * 64;
    int lim = (M - row0) * 16;
    for (int i = threadIdx.x; i < 1024; i += 256) {
        s_t[i]  = (i < lim) ? tl[row0 * 16 + i]  : 0;
        s_tt[i] = (i < lim) ? ttl[row0 * 16 + i] : 0;
    }
    __syncthreads();

    int lr = threadIdx.x >> 2, q = threadIdx.x & 3;
    int r = row0 + lr;
    bool act = r < M;
    int rc = act ? r : row0;

    float a[8];
    {
        uint4 u = *(const uint4*)(Self + (size_t)rc * 32 + q * 8);
        unpack2(u.x, a[0], a[1]); unpack2(u.y, a[2], a[3]);
        unpack2(u.z, a[4], a[5]); unpack2(u.w, a[6], a[7]);
    }
    const int* il  = &s_t[lr * 16];
    const int* ill = &s_tt[lr * 16];
#pragma unroll
    for (int batch = 0; batch < 2; ++batch) {
        uint4 g[8];
#pragma unroll
        for (int j = 0; j < 8; ++j)
            g[j] = *(const uint4*)(T + (size_t)il[batch * 8 + j] * 32 + q * 8);
#pragma unroll
        for (int j = 0; j < 8; ++j) {
            float e0, e1, e2, e3, e4, e5, e6, e7;
            unpack2(g[j].x, e0, e1); unpack2(g[j].y, e2, e3);
            unpack2(g[j].z, e4, e5); unpack2(g[j].w, e6, e7);
            a[0] += e0; a[1] += e1; a[2] += e2; a[3] += e3;
            a[4] += e4; a[5] += e5; a[6] += e6; a[7] += e7;
        }
    }
#pragma unroll
    for (int batch = 0; batch < 2; ++batch) {
        uint4 g[8];
#pragma unroll
        for (int j = 0; j < 8; ++j)
            g[j] = *(const uint4*)(TT + (size_t)ill[batch * 8 + j] * 32 + q * 8);
#pragma unroll
        for (int j = 0; j < 8; ++j) {
            float e0, e1, e2, e3, e4, e5, e6, e7;
            unpack2(g[j].x, e0, e1); unpack2(g[j].y, e2, e3);
            unpack2(g[j].z, e4, e5); unpack2(g[j].w, e6, e7);
            a[0] += e0; a[1] += e1; a[2] += e2; a[3] += e3;
            a[4] += e4; a[5] += e5; a[6] += e6; a[7] += e7;
        }
    }
    if (!is_y) {
        // Segment-sum pull: incoming edges of node rc.
        int c = cnt[rc];
        if (c > ECAP) c = ECAP;
        const int* el = elist + (size_t)rc * ECAP;
        for (int k = 0; k < c; ++k) {
            int e = el[k];
            uint4 g = *(const uint4*)(Yaux + (size_t)e * 32 + q * 8);
            float e0, e1, e2, e3, e4, e5, e6, e7;
            unpack2(g.x, e0, e1); unpack2(g.y, e2, e3);
            unpack2(g.z, e4, e5); unpack2(g.w, e6, e7);
            a[0] += e0; a[1] += e1; a[2] += e2; a[3] += e3;
            a[4] += e4; a[5] += e5; a[6] += e6; a[7] += e7;
        }
        // Overflow fallback accumulator (normally all zeros).
        float4 b0 = *(const float4*)(xacc + (size_t)rc * 32 + q * 8);
        float4 b1 = *(const float4*)(xacc + (size_t)rc * 32 + q * 8 + 4);
        a[0] += b0.x; a[1] += b0.y; a[2] += b0.z; a[3] += b0.w;
        a[4] += b1.x; a[5] += b1.y; a[6] += b1.z; a[7] += b1.w;
    } else {
        int ai = pm_pd[rc];
        uint4 g = *(const uint4*)(Xaux + (size_t)ai * 32 + q * 8);
        float e0, e1, e2, e3, e4, e5, e6, e7;
        unpack2(g.x, e0, e1); unpack2(g.y, e2, e3);
        unpack2(g.z, e4, e5); unpack2(g.w, e6, e7);
        a[0] += e0; a[1] += e1; a[2] += e2; a[3] += e3;
        a[4] += e4; a[5] += e5; a[6] += e6; a[7] += e7;
    }
    if (q >= 2) {
#pragma unroll
        for (int i = 0; i < 8; ++i) a[i] = fmaxf(a[i], 0.f);
    }
    if (act) {
        size_t orow = (size_t)(is_y ? NN + r : r) * 32 + q * 8;
        uint4 o;
        o.x = pack2(a[0], a[1]); o.y = pack2(a[2], a[3]);
        o.z = pack2(a[4], a[5]); o.w = pack2(a[6], a[7]);
        *(uint4*)(pre_h + orow) = o;
    } else {
#pragma unroll
        for (int i = 0; i < 8; ++i) a[i] = 0.f;
    }
#pragma unroll
    for (int i = 0; i < 8; ++i) {
        atomicAdd(&s_sum[q * 8 + i], a[i]);
        atomicAdd(&s_sq[q * 8 + i], a[i] * a[i]);
    }
    __syncthreads();
    if (threadIdx.x < 32) {
        atomicAdd(&ss[threadIdx.x], s_sum[threadIdx.x]);
        atomicAdd(&ss[32 + threadIdx.x], s_sq[threadIdx.x]);
    }
}

__global__ void finalize_stats(
    const float* stats,
    const void* bnxw, const void* bnxb, const void* bnyw, const void* bnyb,
    float* scsh, const int* flagp)
{
    int f32 = *flagp;
    int f = threadIdx.x;
    if (f < 32) {
        float m = stats[f] / (float)NN;
        float var = stats[32 + f] / (float)NN - m * m;
        float inv = rsqrtf(var + 1e-5f);
        float sc = loadf(bnxw, f, f32) * inv;
        scsh[f] = sc; scsh[32 + f] = loadf(bnxb, f, f32) - m * sc;
    } else if (f < 64) {
        int g = f - 32;
        float m = stats[64 + g] / (float)NE;
        float var = stats[96 + g] / (float)NE - m * m;
        float inv = rsqrtf(var + 1e-5f);
        float sc = loadf(bnyw, g, f32) * inv;
        scsh[64 + g] = sc; scsh[96 + g] = loadf(bnyb, g, f32) - m * sc;
    }
}

__global__ __launch_bounds__(256) void apply_bn(
    const u16* __restrict__ pre_h, const float* __restrict__ scsh,
    void* __restrict__ out, const int* __restrict__ flagp)
{
    int f32 = *flagp;
    int tid = blockIdx.x * 256 + threadIdx.x;   // MT*8 threads, 4 elems each
    if (tid >= MT * 8) return;
    int fq = (tid & 7) * 4;
    const float* sc = (tid < NN * 8) ? scsh : scsh + 64;
    ushort4 u = ((const ushort4*)pre_h)[tid];
    float o0 = bf2f(u.x) * sc[fq + 0] + sc[32 + fq + 0];
    float o1 = bf2f(u.y) * sc[fq + 1] + sc[32 + fq + 1];
    float o2 = bf2f(u.z) * sc[fq + 2] + sc[32 + fq + 2];
    float o3 = bf2f(u.w) * sc[fq + 3] + sc[32 + fq + 3];
    if (f32) {
        float4 o; o.x = o0; o.y = o1; o.z = o2; o.w = o3;
        ((float4*)out)[tid] = o;
    } else {
        ushort4 o; o.x = f2bf(o0); o.y = f2bf(o1); o.z = f2bf(o2); o.w = f2bf(o3);
        ((ushort4*)out)[tid] = o;
    }
}

extern "C" void kernel_launch(void* const* d_in, const int* in_sizes, int n_in,
                              void* d_out, int out_size, void* d_ws, size_t ws_size,
                              hipStream_t stream)
{
    const void* x      = d_in[0];
    const void* y      = d_in[1];
    const void* deg_g  = d_in[2];
    const void* deg_lg = d_in[3];
    const int* t_g   = (const int*)d_in[4];
    const int* tt_g  = (const int*)d_in[5];
    const int* t_lg  = (const int*)d_in[6];
    const int* tt_lg = (const int*)d_in[7];
    const int* dst   = (const int*)d_in[8];
    const int* pm_pd = (const int*)d_in[9];

    char* ws = (char*)d_ws;
    int*   flag = (int*)ws;                     // 4 B
    u16* Bfx   = (u16*)(ws + 256);              // 5120 u16 = 10 KB
    u16* Bfy   = Bfx + 5120;                    // 10 KB
    float* bx  = (float*)(ws + 24576);          // 32 f32
    float* by  = bx + 32;
    float* stats = by + 32;                     // 128 f32
    float* scsh  = stats + 128;                 // 128 f32
    u16* Xself = (u16*)(ws + 65536);            // NN*32 = 6.4 MB each
    u16* Xt    = Xself + (size_t)NN * 32;
    u16* Xtt   = Xt    + (size_t)NN * 32;
    u16* Xaux  = Xtt   + (size_t)NN * 32;
    u16* Yself = Xaux  + (size_t)NN * 32;       // NE*32 = 12.8 MB each
    u16* Yt    = Yself + (size_t)NE * 32;
    u16* Ytt   = Yt    + (size_t)NE * 32;
    u16* Yaux  = Ytt   + (size_t)NE * 32;       // 12.8 MB
    float* xacc = (float*)(Yaux + (size_t)NE * 32);  // NN*32 f32 = 12.8 MB (overflow acc)
    u16* pre_h = (u16*)(xacc + (size_t)NN * 32);     // MT*32 bf16 = 19.2 MB
    int* cnt   = (int*)(pre_h + (size_t)MT * 32);    // NN int = 0.4 MB
    int* elist = cnt + NN;                           // NN*ECAP int = 6.4 MB
    // total ~ 116 MB (R2-R4 ran fine at 121.7 MB)

    hipMemsetAsync(stats, 0, 256 * sizeof(float), stream);
    hipMemsetAsync(xacc, 0, (size_t)NN * 32 * sizeof(float), stream);
    hipMemsetAsync(cnt, 0, (size_t)NN * sizeof(int), stream);

    detect_kernel<<<1, 256, 0, stream>>>((const u32*)x, flag);
    prep_kernel<<<41, 256, 0, stream>>>(
        d_in[10], d_in[12], d_in[14], d_in[16], d_in[18], d_in[20],
        d_in[22], d_in[24],
        d_in[11], d_in[13], d_in[15], d_in[17], d_in[19], d_in[21],
        d_in[23], d_in[25],
        Bfx, Bfy, bx, by, flag);
    gemm_side<<<1563, 256, 0, stream>>>(x, Bfx, bx, deg_g,
                                        Xself, Xt, Xtt, Xaux, 6250, flag);
    gemm_side<<<3125, 256, 0, stream>>>(y, Bfy, by, deg_lg,
                                        Yself, Yt, Ytt, Yaux, 12500, flag);
    fill_edges<<<782, 256, 0, stream>>>(dst, cnt, elist, Yaux, xacc);
    gather_fused<<<4688, 256, 0, stream>>>(Xself, Xt, Xtt, Xaux,
                                           Yself, Yt, Ytt, Yaux,
                                           xacc, cnt, elist,
                                           t_g, tt_g, t_lg, tt_lg, pm_pd,
                                           pre_h, stats);
    finalize_stats<<<1, 64, 0, stream>>>(stats, d_in[26], d_in[27], d_in[28],
                                         d_in[29], scsh, flag);
    apply_bn<<<9375, 256, 0, stream>>>(pre_h, scsh, d_out, flag);
}